// Round 2
// baseline (318.378 us; speedup 1.0000x reference)
//
#include <hip/hip_runtime.h>

// MHA: B=2,S=2048,D=1024,H=16,dk=64. fp32 I/O (per reference), bf16 MFMA compute.
// Dispatches: cvt(fp32->bf16), Qproj, Kproj, Vproj(transposed store), flash-attn,
// Oproj(fp32 store).
// ws layout (bf16 elems): Wq|Wk|Wv|Wo (1M each) @0..4M, q_bf @4M (Vt overlays),
// k_bf @8M (O overlays), v_bf @12M, Q @16M, K @20M.  Total 24M elems = 48 MB.

typedef unsigned short bf16_t;
typedef __bf16 bf16x8 __attribute__((ext_vector_type(8)));
typedef float f32x4 __attribute__((ext_vector_type(4)));

#define GLD_LDS(gptr, lptr)                                                    \
    __builtin_amdgcn_global_load_lds(                                          \
        (const __attribute__((address_space(1))) void*)(gptr),                 \
        (__attribute__((address_space(3))) void*)(lptr), 16, 0, 0)

constexpr int DM = 1024;     // d_model
constexpr int NH = 16;       // heads
constexpr int DK = 64;       // head dim
constexpr int SEQ = 2048;
constexpr int MROWS = 2 * SEQ;  // 4096

__device__ __forceinline__ bf16_t f2bf(float f) {
    union { float f; unsigned u; } c; c.f = f;
    unsigned u = c.u + 0x7FFFu + ((c.u >> 16) & 1u);   // RNE, finite values only
    return (bf16_t)(u >> 16);
}

// ---------------------------------------------------------------------------
// fp32 -> bf16 conversion pre-pass, 7 tensors in one dispatch (grid.y = tensor)
// ---------------------------------------------------------------------------
struct CvtArgs {
    const float* src[7];
    bf16_t* dst[7];
    int n[7];
};

__global__ __launch_bounds__(256)
void cvt_kernel(CvtArgs a)
{
    const int ti = blockIdx.y;
    const int base = (blockIdx.x * 256 + threadIdx.x) * 4;
    if (base >= a.n[ti]) return;
    const float4 v = *reinterpret_cast<const float4*>(a.src[ti] + base);
    ushort4 o;
    o.x = f2bf(v.x); o.y = f2bf(v.y); o.z = f2bf(v.z); o.w = f2bf(v.w);
    *reinterpret_cast<ushort4*>(a.dst[ti] + base) = o;
}

// ---------------------------------------------------------------------------
// GEMM: C[m,n] = sum_k A[m,k] * W[n,k] + bias[n]   (torch Linear, W row-major [N,K])
// 128x128 tile, BK=32, 256 thr = 4 waves (2x2), each wave 4x4 MFMA 16x16x32.
// MODE: 0 -> [B,H,S,64] bf16 scatter (Q,K)   1 -> [B,H,64,S] bf16 scatter (V^T)
//       2 -> row-major [M,N] fp32 (final out)
// ---------------------------------------------------------------------------
template<int MODE>
__global__ __launch_bounds__(256)
void gemm_bt_kernel(const bf16_t* __restrict__ A, const bf16_t* __restrict__ W,
                    const float* __restrict__ bias, void* __restrict__ outp)
{
    __shared__ __align__(16) bf16_t Asm[128 * 32];
    __shared__ __align__(16) bf16_t Bsm[128 * 32];

    const int t = threadIdx.x;
    const int wave = t >> 6, lane = t & 63;
    const int lrow = lane & 15, quad = lane >> 4;
    const int wm = wave >> 1, wn = wave & 1;
    const int m0 = blockIdx.y * 128;
    const int n0 = blockIdx.x * 128;

    f32x4 acc[4][4] = {};

    for (int k0 = 0; k0 < DM; k0 += 32) {
        // stage A,B tiles: 8KB each = 512 chunks of 16B; lds dst forced to
        // base+lane*16, so we swizzle WHICH global chunk each lane fetches:
        // row r, stored chunk s holds global k-chunk s ^ ((r>>1)&3)  (bank fix)
#pragma unroll
        for (int i = 0; i < 2; ++i) {
            const int f = i * 256 + t;
            const int row = f >> 2;
            const int cq = (f & 3) ^ ((row >> 1) & 3);
            const int gcol = k0 + cq * 8;
            GLD_LDS(A + (size_t)(m0 + row) * DM + gcol, Asm + f * 8);
            GLD_LDS(W + (size_t)(n0 + row) * DM + gcol, Bsm + f * 8);
        }
        __syncthreads();

        const int sw = (quad ^ ((lrow >> 1) & 3)) * 8;  // swizzled chunk offset
        bf16x8 af[4], bfr[4];
#pragma unroll
        for (int mt = 0; mt < 4; ++mt)
            af[mt] = *reinterpret_cast<const bf16x8*>(Asm + (wm * 64 + mt * 16 + lrow) * 32 + sw);
#pragma unroll
        for (int nt = 0; nt < 4; ++nt)
            bfr[nt] = *reinterpret_cast<const bf16x8*>(Bsm + (wn * 64 + nt * 16 + lrow) * 32 + sw);
#pragma unroll
        for (int mt = 0; mt < 4; ++mt)
#pragma unroll
            for (int nt = 0; nt < 4; ++nt)
                acc[mt][nt] = __builtin_amdgcn_mfma_f32_16x16x32_bf16(
                    af[mt], bfr[nt], acc[mt][nt], 0, 0, 0);
        __syncthreads();
    }

    // epilogue: C/D layout col=lane&15, row=quad*4+reg  [verified m89/m91]
#pragma unroll
    for (int nt = 0; nt < 4; ++nt) {
        const int col = n0 + wn * 64 + nt * 16 + lrow;
        const float bv = bias[col];
#pragma unroll
        for (int mt = 0; mt < 4; ++mt) {
#pragma unroll
            for (int r = 0; r < 4; ++r) {
                const int row = m0 + wm * 64 + mt * 16 + quad * 4 + r;
                const float v = acc[mt][nt][r] + bv;
                if (MODE == 2) {
                    ((float*)outp)[(size_t)row * DM + col] = v;
                } else {
                    const int b_ = row >> 11, s_ = row & 2047;
                    const int h_ = col >> 6, d_ = col & 63;
                    size_t idx;
                    if (MODE == 0)
                        idx = ((size_t)(b_ * NH + h_) * SEQ + s_) * DK + d_;
                    else
                        idx = ((size_t)(b_ * NH + h_) * DK + d_) * SEQ + s_;
                    ((bf16_t*)outp)[idx] = f2bf(v);
                }
            }
        }
    }
}

// ---------------------------------------------------------------------------
// Flash attention. Grid (S/64, H, B), 256 thr = 4 waves, wave owns 16 q rows.
// Q:[B,H,S,64]  K:[B,H,S,64]  Vt:[B,H,64,S]  O:[B,S,1024] (b,s,h*64+d) bf16
// K/V 64x64 tiles staged via global_load_lds with XOR chunk swizzle.
// ---------------------------------------------------------------------------
__global__ __launch_bounds__(256)
void attn_kernel(const bf16_t* __restrict__ Qg, const bf16_t* __restrict__ Kg,
                 const bf16_t* __restrict__ Vg, bf16_t* __restrict__ Og)
{
    __shared__ __align__(16) bf16_t Ksm[64 * 64];
    __shared__ __align__(16) bf16_t Vsm[64 * 64];
    __shared__ __align__(16) bf16_t Psm[4][16 * 64];

    const int t = threadIdx.x;
    const int wave = t >> 6, lane = t & 63;
    const int lrow = lane & 15, quad = lane >> 4;
    const int bb = blockIdx.z, h = blockIdx.y;
    const int q0 = blockIdx.x * 64;
    const size_t head = (size_t)(bb * NH + h) * SEQ * DK;
    const bf16_t* Qh = Qg + head;
    const bf16_t* Kh = Kg + head;
    const bf16_t* Vh = Vg + head;   // [64][SEQ]

    // A-operand frags of Q for this wave's 16 rows: A[m=lane&15][k=quad*8+j]
    bf16x8 qfrag[2];
    {
        const int qrow = q0 + wave * 16 + lrow;
        qfrag[0] = *reinterpret_cast<const bf16x8*>(Qh + (size_t)qrow * DK + quad * 8);
        qfrag[1] = *reinterpret_cast<const bf16x8*>(Qh + (size_t)qrow * DK + 32 + quad * 8);
    }

    float m_i[4], l_i[4];
#pragma unroll
    for (int r = 0; r < 4; ++r) { m_i[r] = -1e30f; l_i[r] = 0.f; }
    f32x4 oacc[4] = {};

    for (int j0 = 0; j0 < SEQ; j0 += 64) {
        // stage K tile (rows j, 64 d) and Vt tile (rows d, 64 j), 8KB each.
        // stored chunk s of row r holds global chunk s ^ (r&7)
#pragma unroll
        for (int i = 0; i < 2; ++i) {
            const int f = i * 256 + t;
            const int row = f >> 3;
            const int cq = (f & 7) ^ (row & 7);
            GLD_LDS(Kh + (size_t)(j0 + row) * DK + cq * 8, Ksm + f * 8);
            GLD_LDS(Vh + (size_t)row * SEQ + j0 + cq * 8, Vsm + f * 8);
        }
        __syncthreads();

        // S = Q K^T  (k-dim = d = 64 -> two MFMAs per 16x16 tile)
        f32x4 sacc[4] = {};
#pragma unroll
        for (int kk = 0; kk < 2; ++kk) {
            const int kq = kk * 4 + quad;
#pragma unroll
            for (int nt = 0; nt < 4; ++nt) {
                const int krow = nt * 16 + lrow;
                bf16x8 kf = *reinterpret_cast<const bf16x8*>(
                    Ksm + krow * 64 + ((kq ^ (lrow & 7)) * 8));
                sacc[nt] = __builtin_amdgcn_mfma_f32_16x16x32_bf16(
                    qfrag[kk], kf, sacc[nt], 0, 0, 0);
            }
        }

        // online softmax; row stats live in the quad's 16 lanes (shfl-xor 1..8)
#pragma unroll
        for (int r = 0; r < 4; ++r) {
            float s0 = sacc[0][r] * 0.125f, s1 = sacc[1][r] * 0.125f;
            float s2 = sacc[2][r] * 0.125f, s3 = sacc[3][r] * 0.125f;
            float mx = fmaxf(fmaxf(s0, s1), fmaxf(s2, s3));
#pragma unroll
            for (int off = 8; off >= 1; off >>= 1)
                mx = fmaxf(mx, __shfl_xor(mx, off, 64));
            const float newm = fmaxf(m_i[r], mx);
            const float alpha = __expf(m_i[r] - newm);
            s0 = __expf(s0 - newm); s1 = __expf(s1 - newm);
            s2 = __expf(s2 - newm); s3 = __expf(s3 - newm);
            float sum = s0 + s1 + s2 + s3;
#pragma unroll
            for (int off = 8; off >= 1; off >>= 1)
                sum += __shfl_xor(sum, off, 64);
            l_i[r] = l_i[r] * alpha + sum;
            m_i[r] = newm;
            sacc[0][r] = s0; sacc[1][r] = s1; sacc[2][r] = s2; sacc[3][r] = s3;
#pragma unroll
            for (int dnt = 0; dnt < 4; ++dnt) oacc[dnt][r] *= alpha;
        }

        // P: C-layout -> A-layout via LDS round trip (m120), swizzled cols
#pragma unroll
        for (int nt = 0; nt < 4; ++nt) {
            const int c = nt * 16 + lrow;
            const int cq = c >> 3, ci = c & 7;
#pragma unroll
            for (int r = 0; r < 4; ++r) {
                const int row = quad * 4 + r;
                Psm[wave][row * 64 + ((cq ^ (row & 7)) * 8) + ci] = f2bf(sacc[nt][r]);
            }
        }

        // O += P @ V   (A = P rows, B = Vt rows, k-dim = j = 64)
#pragma unroll
        for (int kk = 0; kk < 2; ++kk) {
            const int kq = kk * 4 + quad;
            bf16x8 pf = *reinterpret_cast<const bf16x8*>(
                &Psm[wave][lrow * 64 + ((kq ^ (lrow & 7)) * 8)]);
#pragma unroll
            for (int dnt = 0; dnt < 4; ++dnt) {
                const int vrow = dnt * 16 + lrow;
                bf16x8 vf = *reinterpret_cast<const bf16x8*>(
                    Vsm + vrow * 64 + ((kq ^ (lrow & 7)) * 8));
                oacc[dnt] = __builtin_amdgcn_mfma_f32_16x16x32_bf16(
                    pf, vf, oacc[dnt], 0, 0, 0);
            }
        }
        __syncthreads();
    }

    // write O[b, q, h*64+d]
    float inv[4];
#pragma unroll
    for (int r = 0; r < 4; ++r) inv[r] = 1.0f / l_i[r];
    const size_t obase = (size_t)bb * SEQ * DM + (size_t)h * DK;
#pragma unroll
    for (int dnt = 0; dnt < 4; ++dnt) {
#pragma unroll
        for (int r = 0; r < 4; ++r) {
            const int q = q0 + wave * 16 + quad * 4 + r;
            Og[obase + (size_t)q * DM + dnt * 16 + lrow] = f2bf(oacc[dnt][r] * inv[r]);
        }
    }
}

// ---------------------------------------------------------------------------
extern "C" void kernel_launch(void* const* d_in, const int* in_sizes, int n_in,
                              void* d_out, int out_size, void* d_ws, size_t ws_size,
                              hipStream_t stream)
{
    (void)in_sizes; (void)n_in; (void)out_size; (void)ws_size;
    const float* q   = (const float*)d_in[0];
    const float* k   = (const float*)d_in[1];
    const float* v   = (const float*)d_in[2];
    const float* Wq  = (const float*)d_in[3];
    const float* bq  = (const float*)d_in[4];
    const float* Wk  = (const float*)d_in[5];
    const float* bk  = (const float*)d_in[6];
    const float* Wv  = (const float*)d_in[7];
    const float* bv  = (const float*)d_in[8];
    const float* Wo  = (const float*)d_in[9];
    const float* bo  = (const float*)d_in[10];
    float* out = (float*)d_out;

    bf16_t* ws = (bf16_t*)d_ws;
    const size_t MW = 1024 * 1024;              // 1M elems (one weight matrix)
    const size_t PLANE = (size_t)MROWS * DM;    // 4M elems (one activation)
    bf16_t* Wq_bf = ws;
    bf16_t* Wk_bf = ws + 1 * MW;
    bf16_t* Wv_bf = ws + 2 * MW;
    bf16_t* Wo_bf = ws + 3 * MW;
    bf16_t* q_bf  = ws + 4 * MW;                 // Vt overlays after Qproj
    bf16_t* k_bf  = q_bf + PLANE;                // O overlays after Kproj
    bf16_t* v_bf  = q_bf + 2 * PLANE;
    bf16_t* Qws   = q_bf + 3 * PLANE;
    bf16_t* Kws   = q_bf + 4 * PLANE;
    bf16_t* Vtws  = q_bf;                        // overlay
    bf16_t* Ows   = k_bf;                        // overlay

    // fp32 -> bf16 conversions (q,k,v: 4M elems; weights: 1M elems)
    CvtArgs ca;
    ca.src[0] = q;  ca.dst[0] = q_bf;  ca.n[0] = (int)PLANE;
    ca.src[1] = k;  ca.dst[1] = k_bf;  ca.n[1] = (int)PLANE;
    ca.src[2] = v;  ca.dst[2] = v_bf;  ca.n[2] = (int)PLANE;
    ca.src[3] = Wq; ca.dst[3] = Wq_bf; ca.n[3] = (int)MW;
    ca.src[4] = Wk; ca.dst[4] = Wk_bf; ca.n[4] = (int)MW;
    ca.src[5] = Wv; ca.dst[5] = Wv_bf; ca.n[5] = (int)MW;
    ca.src[6] = Wo; ca.dst[6] = Wo_bf; ca.n[6] = (int)MW;
    cvt_kernel<<<dim3((unsigned)(PLANE / (256 * 4)), 7), 256, 0, stream>>>(ca);

    const dim3 gblk(DM / 128, MROWS / 128);    // (8, 32)
    const dim3 thr(256);
    gemm_bt_kernel<0><<<gblk, thr, 0, stream>>>(q_bf, Wq_bf, bq, Qws);
    gemm_bt_kernel<0><<<gblk, thr, 0, stream>>>(k_bf, Wk_bf, bk, Kws);
    gemm_bt_kernel<1><<<gblk, thr, 0, stream>>>(v_bf, Wv_bf, bv, Vtws);
    attn_kernel<<<dim3(SEQ / 64, NH, 2), thr, 0, stream>>>(Qws, Kws, Vtws, Ows);
    gemm_bt_kernel<2><<<gblk, thr, 0, stream>>>(Ows, Wo_bf, bo, out);
}

// Round 3
// 274.886 us; speedup vs baseline: 1.1582x; 1.1582x over previous
//
#include <hip/hip_runtime.h>

// MHA: B=2,S=2048,D=1024,H=16,dk=64. fp32 I/O, bf16 MFMA compute.
// Dispatches: cvt, QKV-proj (z-batched), flash-attn (j-split x2),
// merge, Oproj (128x64 tiles, fp32 store).
// ws layout (bf16 elems): Wq|Wk|Wv|Wo @0..4M, q_bf@4M, k_bf@8M (Ows overlay),
// v_bf@12M, Q@16M, K@20M, Vt@24M, Opart@28M (8M), ml @36M (1MB). Total 73MB.

typedef unsigned short bf16_t;
typedef __bf16 bf16x8 __attribute__((ext_vector_type(8)));
typedef float f32x4 __attribute__((ext_vector_type(4)));
typedef unsigned short u16x8 __attribute__((ext_vector_type(8)));

#define GLD_LDS(gptr, lptr)                                                    \
    __builtin_amdgcn_global_load_lds(                                          \
        (const __attribute__((address_space(1))) void*)(gptr),                 \
        (__attribute__((address_space(3))) void*)(lptr), 16, 0, 0)

constexpr int DM = 1024;
constexpr int NH = 16;
constexpr int DK = 64;
constexpr int SEQ = 2048;
constexpr int MROWS = 2 * SEQ;  // 4096
constexpr float SC2 = 0.125f * 1.44269504088896f;  // 1/sqrt(64) * log2(e)

__device__ __forceinline__ float bf2f(bf16_t v) {
    union { unsigned u; float f; } c; c.u = (unsigned)v << 16; return c.f;
}
__device__ __forceinline__ bf16_t f2bf(float f) {       // RNE
    union { float f; unsigned u; } c; c.f = f;
    unsigned u = c.u + 0x7FFFu + ((c.u >> 16) & 1u);
    return (bf16_t)(u >> 16);
}
__device__ __forceinline__ bf16_t f2bf_rhu(float f) {   // round-half-up, 2 ops
    union { float f; unsigned u; } c; c.f = f;
    return (bf16_t)((c.u + 0x8000u) >> 16);
}

// DPP lane move within 16-lane rows (VALU pipe, no LDS)
template<int CTRL>
__device__ __forceinline__ float dpp_mov(float x) {
    int xi = __builtin_bit_cast(int, x);
    int r = __builtin_amdgcn_update_dpp(xi, xi, CTRL, 0xF, 0xF, false);
    return __builtin_bit_cast(float, r);
}
// reduce over the 16 lanes of a quad-row group: ror:8, ror:4, xor1, xor2
__device__ __forceinline__ float rmax16(float x) {
    x = fmaxf(x, dpp_mov<0x128>(x));
    x = fmaxf(x, dpp_mov<0x124>(x));
    x = fmaxf(x, dpp_mov<0xB1>(x));
    x = fmaxf(x, dpp_mov<0x4E>(x));
    return x;
}
__device__ __forceinline__ float rsum16(float x) {
    x += dpp_mov<0x128>(x);
    x += dpp_mov<0x124>(x);
    x += dpp_mov<0xB1>(x);
    x += dpp_mov<0x4E>(x);
    return x;
}

// ---------------------------------------------------------------------------
// fp32 -> bf16 conversion pre-pass
// ---------------------------------------------------------------------------
struct CvtArgs {
    const float* src[7];
    bf16_t* dst[7];
    int n[7];
};

__global__ __launch_bounds__(256)
void cvt_kernel(CvtArgs a)
{
    const int ti = blockIdx.y;
    const int base = (blockIdx.x * 256 + threadIdx.x) * 4;
    if (base >= a.n[ti]) return;
    const float4 v = *reinterpret_cast<const float4*>(a.src[ti] + base);
    ushort4 o;
    o.x = f2bf(v.x); o.y = f2bf(v.y); o.z = f2bf(v.z); o.w = f2bf(v.w);
    *reinterpret_cast<ushort4*>(a.dst[ti] + base) = o;
}

// ---------------------------------------------------------------------------
// GEMM: C[m,n] = sum_k A[m,k]*W[n,k] + bias[n].  128xBN tile, BK=32,
// 4 waves 2x2, wave = 64 rows x BN/2 cols.  blockIdx.z selects tensor set.
// mode: 0 -> [B,H,S,64] bf16   1 -> [B,H,64,S] bf16   2 -> [M,N] fp32
// ---------------------------------------------------------------------------
struct GemmArgs {
    const bf16_t* A[3];
    const bf16_t* W[3];
    const float*  bias[3];
    void*         out[3];
    int           mode[3];
};

template<int BN>
__global__ __launch_bounds__(256)
void gemm_kernel(GemmArgs ga)
{
    constexpr int NT = BN / 32;
    __shared__ __align__(16) bf16_t Asm[128 * 32];
    __shared__ __align__(16) bf16_t Bsm[BN * 32];

    const int z = blockIdx.z;
    const bf16_t* __restrict__ A = ga.A[z];
    const bf16_t* __restrict__ W = ga.W[z];
    const float* __restrict__ bias = ga.bias[z];
    const int mode = ga.mode[z];

    const int t = threadIdx.x;
    const int wave = t >> 6, lane = t & 63;
    const int lrow = lane & 15, quad = lane >> 4;
    const int wm = wave >> 1, wn = wave & 1;
    const int m0 = blockIdx.y * 128;
    const int n0 = blockIdx.x * BN;

    f32x4 acc[4][NT] = {};

    for (int k0 = 0; k0 < DM; k0 += 32) {
        // stage tiles; swizzle which k-chunk each lane fetches (bank fix):
        // row r, stored chunk s holds global chunk s ^ ((r>>1)&3)
#pragma unroll
        for (int i = 0; i < 2; ++i) {
            const int f = i * 256 + t;
            const int row = f >> 2;
            const int cq = (f & 3) ^ ((row >> 1) & 3);
            GLD_LDS(A + (size_t)(m0 + row) * DM + k0 + cq * 8, Asm + f * 8);
        }
#pragma unroll
        for (int i = 0; i < BN / 64; ++i) {
            const int f = i * 256 + t;
            const int row = f >> 2;
            const int cq = (f & 3) ^ ((row >> 1) & 3);
            GLD_LDS(W + (size_t)(n0 + row) * DM + k0 + cq * 8, Bsm + f * 8);
        }
        __syncthreads();

        const int sw = (quad ^ ((lrow >> 1) & 3)) * 8;
        bf16x8 af[4], bfr[NT];
#pragma unroll
        for (int mt = 0; mt < 4; ++mt)
            af[mt] = *reinterpret_cast<const bf16x8*>(Asm + (wm * 64 + mt * 16 + lrow) * 32 + sw);
#pragma unroll
        for (int nt = 0; nt < NT; ++nt)
            bfr[nt] = *reinterpret_cast<const bf16x8*>(Bsm + (wn * (BN / 2) + nt * 16 + lrow) * 32 + sw);
#pragma unroll
        for (int mt = 0; mt < 4; ++mt)
#pragma unroll
            for (int nt = 0; nt < NT; ++nt)
                acc[mt][nt] = __builtin_amdgcn_mfma_f32_16x16x32_bf16(
                    af[mt], bfr[nt], acc[mt][nt], 0, 0, 0);
        __syncthreads();
    }

    // epilogue: C/D layout col=lane&15, row=quad*4+reg
#pragma unroll
    for (int nt = 0; nt < NT; ++nt) {
        const int col = n0 + wn * (BN / 2) + nt * 16 + lrow;
        const float bv = bias[col];
#pragma unroll
        for (int mt = 0; mt < 4; ++mt) {
#pragma unroll
            for (int r = 0; r < 4; ++r) {
                const int row = m0 + wm * 64 + mt * 16 + quad * 4 + r;
                const float vv = acc[mt][nt][r] + bv;
                if (mode == 2) {
                    ((float*)ga.out[z])[(size_t)row * DM + col] = vv;
                } else {
                    const int b_ = row >> 11, s_ = row & 2047;
                    const int h_ = col >> 6, d_ = col & 63;
                    const size_t idx = (mode == 0)
                        ? ((size_t)(b_ * NH + h_) * SEQ + s_) * DK + d_
                        : ((size_t)(b_ * NH + h_) * DK + d_) * SEQ + s_;
                    ((bf16_t*)ga.out[z])[idx] = f2bf(vv);
                }
            }
        }
    }
}

// ---------------------------------------------------------------------------
// Flash attention, j-split x2.  Grid (S/64, H, B*2); z = b*2+split.
// Block: 4 waves x 16 q-rows; each block does 16 j-tiles (half the seq).
// Writes unnormalized O (bf16) + (m,l) per row for the merge pass.
// ---------------------------------------------------------------------------
__global__ __launch_bounds__(256)
void attn_kernel(const bf16_t* __restrict__ Qg, const bf16_t* __restrict__ Kg,
                 const bf16_t* __restrict__ Vg, bf16_t* __restrict__ Opart,
                 float2* __restrict__ ml)
{
    __shared__ __align__(16) bf16_t Ksm[64 * 64];
    __shared__ __align__(16) bf16_t Vsm[64 * 64];
    __shared__ __align__(16) bf16_t Psm[4][16 * 64];

    const int t = threadIdx.x;
    const int wave = t >> 6, lane = t & 63;
    const int lrow = lane & 15, quad = lane >> 4;
    const int zz = blockIdx.z;
    const int bb = zz >> 1, split = zz & 1;
    const int h = blockIdx.y;
    const int q0 = blockIdx.x * 64;
    const size_t head = (size_t)(bb * NH + h) * SEQ * DK;
    const bf16_t* Qh = Qg + head;
    const bf16_t* Kh = Kg + head;
    const bf16_t* Vh = Vg + head;   // [64][SEQ]

    bf16x8 qfrag[2];
    {
        const int qrow = q0 + wave * 16 + lrow;
        qfrag[0] = *reinterpret_cast<const bf16x8*>(Qh + (size_t)qrow * DK + quad * 8);
        qfrag[1] = *reinterpret_cast<const bf16x8*>(Qh + (size_t)qrow * DK + 32 + quad * 8);
    }

    float m_i[4], l_i[4];
#pragma unroll
    for (int r = 0; r < 4; ++r) { m_i[r] = -1e30f; l_i[r] = 0.f; }
    f32x4 oacc[4] = {};

    const int j_begin = split * (SEQ / 2);
    for (int j0 = j_begin; j0 < j_begin + SEQ / 2; j0 += 64) {
        // stage K (64j x 64d) and Vt (64d x 64j); chunk s of row r <- s^(r&7)
#pragma unroll
        for (int i = 0; i < 2; ++i) {
            const int f = i * 256 + t;
            const int row = f >> 3;
            const int cq = (f & 7) ^ (row & 7);
            GLD_LDS(Kh + (size_t)(j0 + row) * DK + cq * 8, Ksm + f * 8);
            GLD_LDS(Vh + (size_t)row * SEQ + j0 + cq * 8, Vsm + f * 8);
        }
        __syncthreads();

        // S = Q K^T
        f32x4 sacc[4] = {};
#pragma unroll
        for (int kk = 0; kk < 2; ++kk) {
            const int kq = kk * 4 + quad;
#pragma unroll
            for (int nt = 0; nt < 4; ++nt) {
                const int krow = nt * 16 + lrow;
                bf16x8 kf = *reinterpret_cast<const bf16x8*>(
                    Ksm + krow * 64 + ((kq ^ (lrow & 7)) * 8));
                sacc[nt] = __builtin_amdgcn_mfma_f32_16x16x32_bf16(
                    qfrag[kk], kf, sacc[nt], 0, 0, 0);
            }
        }

        // online softmax in log2 domain; DPP reductions (VALU-only)
#pragma unroll
        for (int r = 0; r < 4; ++r) {
            float s0 = sacc[0][r] * SC2, s1 = sacc[1][r] * SC2;
            float s2 = sacc[2][r] * SC2, s3 = sacc[3][r] * SC2;
            float mx = rmax16(fmaxf(fmaxf(s0, s1), fmaxf(s2, s3)));
            const float newm = fmaxf(m_i[r], mx);
            const float alpha = __builtin_amdgcn_exp2f(m_i[r] - newm);
            s0 = __builtin_amdgcn_exp2f(s0 - newm);
            s1 = __builtin_amdgcn_exp2f(s1 - newm);
            s2 = __builtin_amdgcn_exp2f(s2 - newm);
            s3 = __builtin_amdgcn_exp2f(s3 - newm);
            const float sum = rsum16((s0 + s1) + (s2 + s3));
            l_i[r] = l_i[r] * alpha + sum;
            m_i[r] = newm;
            sacc[0][r] = s0; sacc[1][r] = s1; sacc[2][r] = s2; sacc[3][r] = s3;
#pragma unroll
            for (int dnt = 0; dnt < 4; ++dnt) oacc[dnt][r] *= alpha;
        }

        // P: C-layout -> A-layout via LDS, swizzled cols
#pragma unroll
        for (int nt = 0; nt < 4; ++nt) {
            const int c = nt * 16 + lrow;
            const int cq = c >> 3, ci = c & 7;
#pragma unroll
            for (int r = 0; r < 4; ++r) {
                const int row = quad * 4 + r;
                Psm[wave][row * 64 + ((cq ^ (row & 7)) * 8) + ci] = f2bf_rhu(sacc[nt][r]);
            }
        }

        // O += P @ V
#pragma unroll
        for (int kk = 0; kk < 2; ++kk) {
            const int kq = kk * 4 + quad;
            bf16x8 pf = *reinterpret_cast<const bf16x8*>(
                &Psm[wave][lrow * 64 + ((kq ^ (lrow & 7)) * 8)]);
#pragma unroll
            for (int dnt = 0; dnt < 4; ++dnt) {
                const int vrow = dnt * 16 + lrow;
                bf16x8 vf = *reinterpret_cast<const bf16x8*>(
                    Vsm + vrow * 64 + ((kq ^ (lrow & 7)) * 8));
                oacc[dnt] = __builtin_amdgcn_mfma_f32_16x16x32_bf16(
                    pf, vf, oacc[dnt], 0, 0, 0);
            }
        }
        __syncthreads();
    }

    // unnormalized partial write: [split][b][h][q][d]
    const size_t pbase = ((size_t)((split * 2 + bb) * NH + h)) * SEQ * DK;
#pragma unroll
    for (int dnt = 0; dnt < 4; ++dnt) {
#pragma unroll
        for (int r = 0; r < 4; ++r) {
            const int q = q0 + wave * 16 + quad * 4 + r;
            Opart[pbase + (size_t)q * DK + dnt * 16 + lrow] = f2bf_rhu(oacc[dnt][r]);
        }
    }
    if (lrow == 0) {
        const int mlbase = ((split * 2 + bb) * NH + h) * SEQ;
#pragma unroll
        for (int r = 0; r < 4; ++r) {
            const int q = q0 + wave * 16 + quad * 4 + r;
            ml[mlbase + q] = make_float2(m_i[r], l_i[r]);
        }
    }
}

// ---------------------------------------------------------------------------
// Merge the two j-split partials -> Ows [b, q, h*64+d] bf16
// ---------------------------------------------------------------------------
__global__ __launch_bounds__(256)
void merge_kernel(const bf16_t* __restrict__ Opart, const float2* __restrict__ ml,
                  bf16_t* __restrict__ Og)
{
    const int tid = blockIdx.x * 256 + threadIdx.x;   // 512K threads, 8 elems each
    const int g = tid >> 3;                           // (b,h,q), 65536 of them
    const int d0 = (tid & 7) * 8;
    const float2 ml0 = ml[g];
    const float2 ml1 = ml[65536 + g];
    const float m = fmaxf(ml0.x, ml1.x);
    const float w0 = __builtin_amdgcn_exp2f(ml0.x - m);
    const float w1 = __builtin_amdgcn_exp2f(ml1.x - m);
    const float inv = 1.0f / (ml0.y * w0 + ml1.y * w1);
    const size_t base = (size_t)g * DK + d0;
    const u16x8 a = *reinterpret_cast<const u16x8*>(Opart + base);
    const u16x8 b = *reinterpret_cast<const u16x8*>(Opart + base + 4194304);
    u16x8 o;
#pragma unroll
    for (int i = 0; i < 8; ++i)
        o[i] = f2bf((bf2f(a[i]) * w0 + bf2f(b[i]) * w1) * inv);
    const int b_ = g >> 15, h_ = (g >> 11) & 15, q_ = g & 2047;
    *reinterpret_cast<u16x8*>(Og + ((size_t)b_ * SEQ + q_) * DM + h_ * DK + d0) = o;
}

// ---------------------------------------------------------------------------
extern "C" void kernel_launch(void* const* d_in, const int* in_sizes, int n_in,
                              void* d_out, int out_size, void* d_ws, size_t ws_size,
                              hipStream_t stream)
{
    (void)in_sizes; (void)n_in; (void)out_size; (void)ws_size;
    const float* q   = (const float*)d_in[0];
    const float* k   = (const float*)d_in[1];
    const float* v   = (const float*)d_in[2];
    const float* Wq  = (const float*)d_in[3];
    const float* bq  = (const float*)d_in[4];
    const float* Wk  = (const float*)d_in[5];
    const float* bk  = (const float*)d_in[6];
    const float* Wv  = (const float*)d_in[7];
    const float* bv  = (const float*)d_in[8];
    const float* Wo  = (const float*)d_in[9];
    const float* bo  = (const float*)d_in[10];
    float* out = (float*)d_out;

    bf16_t* ws = (bf16_t*)d_ws;
    const size_t MW = 1024 * 1024;
    const size_t PLANE = (size_t)MROWS * DM;    // 4M
    bf16_t* Wq_bf = ws;
    bf16_t* Wk_bf = ws + 1 * MW;
    bf16_t* Wv_bf = ws + 2 * MW;
    bf16_t* Wo_bf = ws + 3 * MW;
    bf16_t* q_bf  = ws + 4 * MW;
    bf16_t* k_bf  = ws + 8 * MW;                // Ows overlays after QKV-proj
    bf16_t* v_bf  = ws + 12 * MW;
    bf16_t* Qws   = ws + 16 * MW;
    bf16_t* Kws   = ws + 20 * MW;
    bf16_t* Vtws  = ws + 24 * MW;
    bf16_t* Opart = ws + 28 * MW;               // 8M elems (2 splits)
    float2* mlws  = (float2*)(ws + 36 * MW);    // 2*65536 float2 = 1MB
    bf16_t* Ows   = k_bf;

    CvtArgs ca;
    ca.src[0] = q;  ca.dst[0] = q_bf;  ca.n[0] = (int)PLANE;
    ca.src[1] = k;  ca.dst[1] = k_bf;  ca.n[1] = (int)PLANE;
    ca.src[2] = v;  ca.dst[2] = v_bf;  ca.n[2] = (int)PLANE;
    ca.src[3] = Wq; ca.dst[3] = Wq_bf; ca.n[3] = (int)MW;
    ca.src[4] = Wk; ca.dst[4] = Wk_bf; ca.n[4] = (int)MW;
    ca.src[5] = Wv; ca.dst[5] = Wv_bf; ca.n[5] = (int)MW;
    ca.src[6] = Wo; ca.dst[6] = Wo_bf; ca.n[6] = (int)MW;
    cvt_kernel<<<dim3((unsigned)(PLANE / (256 * 4)), 7), 256, 0, stream>>>(ca);

    // Q/K/V projections, one dispatch (z = tensor)
    GemmArgs g1{};
    g1.A[0] = q_bf; g1.W[0] = Wq_bf; g1.bias[0] = bq; g1.out[0] = Qws;  g1.mode[0] = 0;
    g1.A[1] = k_bf; g1.W[1] = Wk_bf; g1.bias[1] = bk; g1.out[1] = Kws;  g1.mode[1] = 0;
    g1.A[2] = v_bf; g1.W[2] = Wv_bf; g1.bias[2] = bv; g1.out[2] = Vtws; g1.mode[2] = 1;
    gemm_kernel<128><<<dim3(DM / 128, MROWS / 128, 3), 256, 0, stream>>>(g1);

    attn_kernel<<<dim3(SEQ / 64, NH, 4), 256, 0, stream>>>(Qws, Kws, Vtws, Opart, mlws);
    merge_kernel<<<dim3(512 * 1024 / 256), 256, 0, stream>>>(Opart, mlws, Ows);

    GemmArgs g2{};
    g2.A[0] = Ows; g2.W[0] = Wo_bf; g2.bias[0] = bo; g2.out[0] = out; g2.mode[0] = 2;
    gemm_kernel<64><<<dim3(DM / 64, MROWS / 128, 1), 256, 0, stream>>>(g2);
}

// Round 4
// 251.959 us; speedup vs baseline: 1.2636x; 1.0910x over previous
//
#include <hip/hip_runtime.h>

// MHA: B=2,S=2048,D=1024,H=16,dk=64. fp32 I/O, bf16 MFMA compute.
// Dispatches: cvt, QKV-proj (z-batched, Q pre-scaled by 1/8*log2e),
// flash-attn (S^T/O^T operand-swapped, j-split x2), merge, Oproj (fp32 out).
// ws (bf16 elems): Wq|Wk|Wv|Wo @0..4M, q_bf@4M, k_bf@8M (Ows overlay),
// v_bf@12M, Q@16M, K@20M, Vt(tiled)@24M, Opart@28M (8M), ml@36M.

typedef unsigned short bf16_t;
typedef __bf16 bf16x8 __attribute__((ext_vector_type(8)));
typedef float f32x4 __attribute__((ext_vector_type(4)));
typedef unsigned short u16x8 __attribute__((ext_vector_type(8)));

#define GLD_LDS(gptr, lptr)                                                    \
    __builtin_amdgcn_global_load_lds(                                          \
        (const __attribute__((address_space(1))) void*)(gptr),                 \
        (__attribute__((address_space(3))) void*)(lptr), 16, 0, 0)

constexpr int DM = 1024;
constexpr int NH = 16;
constexpr int DK = 64;
constexpr int SEQ = 2048;
constexpr int MROWS = 2 * SEQ;  // 4096
constexpr float SC2 = 0.125f * 1.44269504088896f;  // 1/sqrt(64) * log2(e)

__device__ __forceinline__ float bf2f(bf16_t v) {
    union { unsigned u; float f; } c; c.u = (unsigned)v << 16; return c.f;
}
__device__ __forceinline__ bf16_t f2bf(float f) {       // RNE
    union { float f; unsigned u; } c; c.f = f;
    unsigned u = c.u + 0x7FFFu + ((c.u >> 16) & 1u);
    return (bf16_t)(u >> 16);
}
// round-half-up pack of two floats -> two bf16 in one dword (lo=a, hi=b)
__device__ __forceinline__ unsigned pack_bf2(float a, float b) {
    unsigned ua = __builtin_bit_cast(unsigned, a) + 0x8000u;
    unsigned ub = __builtin_bit_cast(unsigned, b) + 0x8000u;
    return (ua >> 16) | (ub & 0xFFFF0000u);
}

// ---------------------------------------------------------------------------
// fp32 -> bf16 conversion pre-pass
// ---------------------------------------------------------------------------
struct CvtArgs {
    const float* src[7];
    bf16_t* dst[7];
    int n[7];
};

__global__ __launch_bounds__(256)
void cvt_kernel(CvtArgs a)
{
    const int ti = blockIdx.y;
    const int base = (blockIdx.x * 256 + threadIdx.x) * 4;
    if (base >= a.n[ti]) return;
    const float4 v = *reinterpret_cast<const float4*>(a.src[ti] + base);
    ushort4 o;
    o.x = f2bf(v.x); o.y = f2bf(v.y); o.z = f2bf(v.z); o.w = f2bf(v.w);
    *reinterpret_cast<ushort4*>(a.dst[ti] + base) = o;
}

// ---------------------------------------------------------------------------
// GEMM: C[m,n] = (sum_k A[m,k]*W[n,k] + bias[n]) * scale.  128xBN tile, BK=32.
// mode: 0 -> [B,H,S,64] bf16 scatter (Q,K)
//       1 -> [B,H,S/64,64d,64s] bf16 TILED (V^T), 4-wide packed stores
//       2 -> [M,N] fp32 (final out)
// ---------------------------------------------------------------------------
struct GemmArgs {
    const bf16_t* A[3];
    const bf16_t* W[3];
    const float*  bias[3];
    void*         out[3];
    int           mode[3];
    float         scale[3];
};

template<int BN>
__global__ __launch_bounds__(256)
void gemm_kernel(GemmArgs ga)
{
    constexpr int NT = BN / 32;
    __shared__ __align__(16) bf16_t Asm[128 * 32];
    __shared__ __align__(16) bf16_t Bsm[BN * 32];

    const int z = blockIdx.z;
    const bf16_t* __restrict__ A = ga.A[z];
    const bf16_t* __restrict__ W = ga.W[z];
    const float* __restrict__ bias = ga.bias[z];
    const int mode = ga.mode[z];
    const float scale = ga.scale[z];

    const int t = threadIdx.x;
    const int wave = t >> 6, lane = t & 63;
    const int lrow = lane & 15, quad = lane >> 4;
    const int wm = wave >> 1, wn = wave & 1;
    const int m0 = blockIdx.y * 128;
    const int n0 = blockIdx.x * BN;

    f32x4 acc[4][NT] = {};

    for (int k0 = 0; k0 < DM; k0 += 32) {
        // stage tiles; row r, stored chunk s holds global chunk s ^ ((r>>1)&3)
#pragma unroll
        for (int i = 0; i < 2; ++i) {
            const int f = i * 256 + t;
            const int row = f >> 2;
            const int cq = (f & 3) ^ ((row >> 1) & 3);
            GLD_LDS(A + (size_t)(m0 + row) * DM + k0 + cq * 8, Asm + f * 8);
        }
#pragma unroll
        for (int i = 0; i < BN / 64; ++i) {
            const int f = i * 256 + t;
            const int row = f >> 2;
            const int cq = (f & 3) ^ ((row >> 1) & 3);
            GLD_LDS(W + (size_t)(n0 + row) * DM + k0 + cq * 8, Bsm + f * 8);
        }
        __syncthreads();

        const int sw = (quad ^ ((lrow >> 1) & 3)) * 8;
        bf16x8 af[4], bfr[NT];
#pragma unroll
        for (int mt = 0; mt < 4; ++mt)
            af[mt] = *reinterpret_cast<const bf16x8*>(Asm + (wm * 64 + mt * 16 + lrow) * 32 + sw);
#pragma unroll
        for (int nt = 0; nt < NT; ++nt)
            bfr[nt] = *reinterpret_cast<const bf16x8*>(Bsm + (wn * (BN / 2) + nt * 16 + lrow) * 32 + sw);
#pragma unroll
        for (int mt = 0; mt < 4; ++mt)
#pragma unroll
            for (int nt = 0; nt < NT; ++nt)
                acc[mt][nt] = __builtin_amdgcn_mfma_f32_16x16x32_bf16(
                    af[mt], bfr[nt], acc[mt][nt], 0, 0, 0);
        __syncthreads();
    }

    // epilogue: C/D layout col=lane&15, row=quad*4+reg
#pragma unroll
    for (int nt = 0; nt < NT; ++nt) {
        const int col = n0 + wn * (BN / 2) + nt * 16 + lrow;
        const float bv = bias[col];
#pragma unroll
        for (int mt = 0; mt < 4; ++mt) {
            const int row0 = m0 + wm * 64 + mt * 16 + quad * 4;
            float vv[4];
#pragma unroll
            for (int r = 0; r < 4; ++r) vv[r] = (acc[mt][nt][r] + bv) * scale;
            if (mode == 2) {
#pragma unroll
                for (int r = 0; r < 4; ++r)
                    ((float*)ga.out[z])[(size_t)(row0 + r) * DM + col] = vv[r];
            } else if (mode == 0) {
#pragma unroll
                for (int r = 0; r < 4; ++r) {
                    const int row = row0 + r;
                    const int b_ = row >> 11, s_ = row & 2047;
                    const int h_ = col >> 6, d_ = col & 63;
                    ((bf16_t*)ga.out[z])[((size_t)(b_ * NH + h_) * SEQ + s_) * DK + d_] = f2bf(vv[r]);
                }
            } else {
                // tiled V^T: [b,h][s>>6][d*64 + (s&63)], rows r are consecutive s
                const int b_ = row0 >> 11, s_ = row0 & 2047;
                const int h_ = col >> 6, d_ = col & 63;
                uint2 pk;
                pk.x = pack_bf2(vv[0], vv[1]);
                pk.y = pack_bf2(vv[2], vv[3]);
                const size_t idx = (size_t)(b_ * NH + h_) * SEQ * DK
                                 + (size_t)(s_ >> 6) * 4096 + d_ * 64 + (s_ & 63);
                *reinterpret_cast<uint2*>((bf16_t*)ga.out[z] + idx) = pk;
            }
        }
    }
}

// ---------------------------------------------------------------------------
// Flash attention, operand-swapped (S^T = K Q^T, O^T = Vt P^T), j-split x2.
// Grid (S/64, H, B*2); block 4 waves x 16 q.  Per-lane softmax state at q=lrow.
// Q:[B,H,S,64] (pre-scaled by SC2)  K:[B,H,S,64]  Vt tiled:[B,H][S/64][64d][64s]
// ---------------------------------------------------------------------------
__global__ __launch_bounds__(256)
void attn_kernel(const bf16_t* __restrict__ Qg, const bf16_t* __restrict__ Kg,
                 const bf16_t* __restrict__ Vg, bf16_t* __restrict__ Opart,
                 float2* __restrict__ ml)
{
    __shared__ __align__(16) bf16_t Ksm[64 * 64];
    __shared__ __align__(16) bf16_t Vsm[64 * 64];
    __shared__ __align__(16) bf16_t Psm[4][16 * 64];

    const int t = threadIdx.x;
    const int wave = t >> 6, lane = t & 63;
    const int lrow = lane & 15, quad = lane >> 4;
    const int zz = blockIdx.z;
    const int bb = zz >> 1, split = zz & 1;
    const int h = blockIdx.y;
    const int q0 = blockIdx.x * 64;
    const size_t head = (size_t)(bb * NH + h) * SEQ * DK;
    const bf16_t* Qh = Qg + head;
    const bf16_t* Kh = Kg + head;
    const bf16_t* Vh = Vg + head;   // tiled [S/64][64d][64s]

    // B-operand frags of Q (pre-scaled): B[n=q=lrow][k=quad*8+j]
    const int myq = q0 + wave * 16 + lrow;
    bf16x8 qfrag[2];
    qfrag[0] = *reinterpret_cast<const bf16x8*>(Qh + (size_t)myq * DK + quad * 8);
    qfrag[1] = *reinterpret_cast<const bf16x8*>(Qh + (size_t)myq * DK + 32 + quad * 8);

    float m_i = -1e30f, l_i = 0.f;     // per-lane, q = lrow (replicated x4 quads)
    f32x4 oacc[4] = {};                // O^T: d = dnt*16+quad*4+r, q = lrow

    bf16_t* Pw = Psm[wave];
    const int swz = lrow & 7;

    const int j_begin = split * (SEQ / 2);
    for (int j0 = j_begin; j0 < j_begin + SEQ / 2; j0 += 64) {
        // stage K (64j x 64d rows) and tiled Vt (contiguous 8KB tile)
        const bf16_t* Vt_tile = Vh + (size_t)(j0 >> 6) * 4096;
#pragma unroll
        for (int i = 0; i < 2; ++i) {
            const int f = i * 256 + t;
            const int row = f >> 3;
            const int cq = (f & 7) ^ (row & 7);
            GLD_LDS(Kh + (size_t)(j0 + row) * DK + cq * 8, Ksm + f * 8);
            GLD_LDS(Vt_tile + row * 64 + cq * 8, Vsm + f * 8);
        }
        __syncthreads();

        // S^T = K Q^T : A = K rows (m=j), B = qfrag (n=q)
        f32x4 sacc[4] = {};
#pragma unroll
        for (int kk = 0; kk < 2; ++kk) {
#pragma unroll
            for (int nt = 0; nt < 4; ++nt) {
                bf16x8 kf = *reinterpret_cast<const bf16x8*>(
                    Ksm + (nt * 16 + lrow) * 64 + (((kk * 4 + quad) ^ swz) * 8));
                sacc[nt] = __builtin_amdgcn_mfma_f32_16x16x32_bf16(
                    kf, qfrag[kk], sacc[nt], 0, 0, 0);
            }
        }

        // online softmax over 16 in-lane values + cross-quad (xor16, xor32)
        float mx = fmaxf(fmaxf(fmaxf(sacc[0][0], sacc[0][1]), fmaxf(sacc[0][2], sacc[0][3])),
                         fmaxf(fmaxf(sacc[1][0], sacc[1][1]), fmaxf(sacc[1][2], sacc[1][3])));
        mx = fmaxf(mx, fmaxf(fmaxf(fmaxf(sacc[2][0], sacc[2][1]), fmaxf(sacc[2][2], sacc[2][3])),
                             fmaxf(fmaxf(sacc[3][0], sacc[3][1]), fmaxf(sacc[3][2], sacc[3][3]))));
        mx = fmaxf(mx, __shfl_xor(mx, 16, 64));
        mx = fmaxf(mx, __shfl_xor(mx, 32, 64));
        const float newm = fmaxf(m_i, mx);
        const float alpha = __builtin_amdgcn_exp2f(m_i - newm);
        float psum = 0.f;
#pragma unroll
        for (int nt = 0; nt < 4; ++nt) {
#pragma unroll
            for (int r = 0; r < 4; ++r) {
                const float p = __builtin_amdgcn_exp2f(sacc[nt][r] - newm);
                sacc[nt][r] = p;
                psum += p;
            }
        }
        psum += __shfl_xor(psum, 16, 64);
        psum += __shfl_xor(psum, 32, 64);
        l_i = l_i * alpha + psum;
        m_i = newm;
#pragma unroll
        for (int dnt = 0; dnt < 4; ++dnt)
#pragma unroll
            for (int r = 0; r < 4; ++r) oacc[dnt][r] *= alpha;

        // P store: row-major P[q=16][j=64] per wave, 8-elem-chunk XOR swizzle.
        // lane holds P[q=lrow][j=nt*16+quad*4+r] -> one b64 per nt.
#pragma unroll
        for (int nt = 0; nt < 4; ++nt) {
            uint2 pk;
            pk.x = pack_bf2(sacc[nt][0], sacc[nt][1]);
            pk.y = pack_bf2(sacc[nt][2], sacc[nt][3]);
            const int chunk = (nt * 2 + (quad >> 1)) ^ swz;
            *reinterpret_cast<uint2*>(Pw + lrow * 64 + chunk * 8 + (quad & 1) * 4) = pk;
        }

        // O^T += Vt P^T : A = Vt rows (m=d), B = P rows (n=q)
#pragma unroll
        for (int kk = 0; kk < 2; ++kk) {
            bf16x8 pf = *reinterpret_cast<const bf16x8*>(
                Pw + lrow * 64 + (((kk * 4 + quad) ^ swz) * 8));
#pragma unroll
            for (int dnt = 0; dnt < 4; ++dnt) {
                bf16x8 vf = *reinterpret_cast<const bf16x8*>(
                    Vsm + (dnt * 16 + lrow) * 64 + (((kk * 4 + quad) ^ swz) * 8));
                oacc[dnt] = __builtin_amdgcn_mfma_f32_16x16x32_bf16(
                    vf, pf, oacc[dnt], 0, 0, 0);
            }
        }
        __syncthreads();
    }

    // unnormalized partial write: Opart[(split*2+b)*NH+h][q][d], 4 d packed
    const size_t pbase = ((size_t)((split * 2 + bb) * NH + h)) * SEQ * DK
                       + (size_t)myq * DK;
#pragma unroll
    for (int dnt = 0; dnt < 4; ++dnt) {
        uint2 pk;
        pk.x = pack_bf2(oacc[dnt][0], oacc[dnt][1]);
        pk.y = pack_bf2(oacc[dnt][2], oacc[dnt][3]);
        *reinterpret_cast<uint2*>(Opart + pbase + dnt * 16 + quad * 4) = pk;
    }
    if (quad == 0) {
        const int mlbase = ((split * 2 + bb) * NH + h) * SEQ;
        ml[mlbase + myq] = make_float2(m_i, l_i);
    }
}

// ---------------------------------------------------------------------------
// Merge the two j-split partials -> Ows [b, q, h*64+d] bf16
// ---------------------------------------------------------------------------
__global__ __launch_bounds__(256)
void merge_kernel(const bf16_t* __restrict__ Opart, const float2* __restrict__ ml,
                  bf16_t* __restrict__ Og)
{
    const int tid = blockIdx.x * 256 + threadIdx.x;   // 512K threads, 8 elems each
    const int g = tid >> 3;                           // (b,h,q), 65536 of them
    const int d0 = (tid & 7) * 8;
    const float2 ml0 = ml[g];
    const float2 ml1 = ml[65536 + g];
    const float m = fmaxf(ml0.x, ml1.x);
    const float w0 = __builtin_amdgcn_exp2f(ml0.x - m);
    const float w1 = __builtin_amdgcn_exp2f(ml1.x - m);
    const float inv = 1.0f / (ml0.y * w0 + ml1.y * w1);
    const size_t base = (size_t)g * DK + d0;
    const u16x8 a = *reinterpret_cast<const u16x8*>(Opart + base);
    const u16x8 b = *reinterpret_cast<const u16x8*>(Opart + base + 4194304);
    u16x8 o;
#pragma unroll
    for (int i = 0; i < 8; ++i)
        o[i] = f2bf((bf2f(a[i]) * w0 + bf2f(b[i]) * w1) * inv);
    const int b_ = g >> 15, h_ = (g >> 11) & 15, q_ = g & 2047;
    *reinterpret_cast<u16x8*>(Og + ((size_t)b_ * SEQ + q_) * DM + h_ * DK + d0) = o;
}

// ---------------------------------------------------------------------------
extern "C" void kernel_launch(void* const* d_in, const int* in_sizes, int n_in,
                              void* d_out, int out_size, void* d_ws, size_t ws_size,
                              hipStream_t stream)
{
    (void)in_sizes; (void)n_in; (void)out_size; (void)ws_size;
    const float* q   = (const float*)d_in[0];
    const float* k   = (const float*)d_in[1];
    const float* v   = (const float*)d_in[2];
    const float* Wq  = (const float*)d_in[3];
    const float* bq  = (const float*)d_in[4];
    const float* Wk  = (const float*)d_in[5];
    const float* bk  = (const float*)d_in[6];
    const float* Wv  = (const float*)d_in[7];
    const float* bv  = (const float*)d_in[8];
    const float* Wo  = (const float*)d_in[9];
    const float* bo  = (const float*)d_in[10];
    float* out = (float*)d_out;

    bf16_t* ws = (bf16_t*)d_ws;
    const size_t MW = 1024 * 1024;
    const size_t PLANE = (size_t)MROWS * DM;    // 4M
    bf16_t* Wq_bf = ws;
    bf16_t* Wk_bf = ws + 1 * MW;
    bf16_t* Wv_bf = ws + 2 * MW;
    bf16_t* Wo_bf = ws + 3 * MW;
    bf16_t* q_bf  = ws + 4 * MW;
    bf16_t* k_bf  = ws + 8 * MW;                // Ows overlays after QKV-proj
    bf16_t* v_bf  = ws + 12 * MW;
    bf16_t* Qws   = ws + 16 * MW;
    bf16_t* Kws   = ws + 20 * MW;
    bf16_t* Vtws  = ws + 24 * MW;               // tiled
    bf16_t* Opart = ws + 28 * MW;               // 8M elems (2 splits)
    float2* mlws  = (float2*)(ws + 36 * MW);
    bf16_t* Ows   = k_bf;

    CvtArgs ca;
    ca.src[0] = q;  ca.dst[0] = q_bf;  ca.n[0] = (int)PLANE;
    ca.src[1] = k;  ca.dst[1] = k_bf;  ca.n[1] = (int)PLANE;
    ca.src[2] = v;  ca.dst[2] = v_bf;  ca.n[2] = (int)PLANE;
    ca.src[3] = Wq; ca.dst[3] = Wq_bf; ca.n[3] = (int)MW;
    ca.src[4] = Wk; ca.dst[4] = Wk_bf; ca.n[4] = (int)MW;
    ca.src[5] = Wv; ca.dst[5] = Wv_bf; ca.n[5] = (int)MW;
    ca.src[6] = Wo; ca.dst[6] = Wo_bf; ca.n[6] = (int)MW;
    cvt_kernel<<<dim3((unsigned)(PLANE / (256 * 4)), 7), 256, 0, stream>>>(ca);

    // Q/K/V projections, one dispatch (z = tensor). Q pre-scaled into log2 domain.
    GemmArgs g1{};
    g1.A[0] = q_bf; g1.W[0] = Wq_bf; g1.bias[0] = bq; g1.out[0] = Qws;  g1.mode[0] = 0; g1.scale[0] = SC2;
    g1.A[1] = k_bf; g1.W[1] = Wk_bf; g1.bias[1] = bk; g1.out[1] = Kws;  g1.mode[1] = 0; g1.scale[1] = 1.0f;
    g1.A[2] = v_bf; g1.W[2] = Wv_bf; g1.bias[2] = bv; g1.out[2] = Vtws; g1.mode[2] = 1; g1.scale[2] = 1.0f;
    gemm_kernel<128><<<dim3(DM / 128, MROWS / 128, 3), 256, 0, stream>>>(g1);

    attn_kernel<<<dim3(SEQ / 64, NH, 4), 256, 0, stream>>>(Qws, Kws, Vtws, Opart, mlws);
    merge_kernel<<<dim3(512 * 1024 / 256), 256, 0, stream>>>(Opart, mlws, Ows);

    GemmArgs g2{};
    g2.A[0] = Ows; g2.W[0] = Wo_bf; g2.bias[0] = bo; g2.out[0] = out; g2.mode[0] = 2; g2.scale[0] = 1.0f;
    gemm_kernel<64><<<dim3(DM / 64, MROWS / 128, 1), 256, 0, stream>>>(g2);
}